// Round 5
// baseline (559.644 us; speedup 1.0000x reference)
//
#include <hip/hip_runtime.h>
#include <math.h>

#define N 512
#define NN (N * N)
#define C 16
#define K 262144
#define LOG2N 9
#define NCOL 8

// skewed LDS addressing (float4-element units): +1 every 16 elements.
#define SK(e) ((e) + ((e) >> 4))
#define LROW 544   // 512 + 32 skew slack

// ============ fused front-end: hist + scan + payload, ONE kernel ============
// 1024 blocks x 256 threads (1 point/thread). Co-residency for the grid
// barrier: 20 KB LDS -> 8 blocks/CU capacity = 2048 >= 1024 (2x slack).

__device__ __forceinline__ void gridbar(int* bar, int target) {
    __syncthreads();
    if (threadIdx.x == 0) {
        __threadfence();
        __hip_atomic_fetch_add(bar, 1, __ATOMIC_ACQ_REL, __HIP_MEMORY_SCOPE_AGENT);
        while (__hip_atomic_load(bar, __ATOMIC_ACQUIRE, __HIP_MEMORY_SCOPE_AGENT) < target) {
            __builtin_amdgcn_s_sleep(8);
        }
        __threadfence();
    }
    __syncthreads();
}

__global__ __launch_bounds__(256) void scan_pay_kernel(const float2* __restrict__ traj,
                                                       const float* __restrict__ dcf,
                                                       const float* __restrict__ xr,
                                                       const float* __restrict__ xi,
                                                       int* __restrict__ count,
                                                       int* __restrict__ offs,
                                                       int* __restrict__ cursor,
                                                       int* __restrict__ chunk_sum,
                                                       int* __restrict__ bar,
                                                       float2* __restrict__ pay) {
    __shared__ float tR[128][17];   // [point][channel], +1 pad -> conflict-free
    __shared__ float tI[128][17];
    __shared__ int   sd[256];
    __shared__ int   sp[256];
    __shared__ float sw[256];
    int t = threadIdx.x;
    int b = blockIdx.x;
    int i = b * 256 + t;            // this thread's point AND this block's cell range

    // ---- phase A: histogram; cl/w stay in registers (no cell/sdcf arrays) ----
    float2 tr = traj[i];
    int iy = __float2int_rn((tr.x + 0.5f) * (float)N) & (N - 1);
    int ix = __float2int_rn((tr.y + 0.5f) * (float)N) & (N - 1);
    int cl = iy * N + ix;
    float w = dcf[i] * (((iy + ix) & 1) ? -1.0f : 1.0f);   // ifftshift sign folded
    atomicAdd(&count[cl], 1);
    gridbar(bar, 1024);

    // ---- phase B: local inclusive scan of this block's 256 cells ----
    int cnt = count[i];             // coalesced
    sd[t] = cnt;
    __syncthreads();
    for (int d = 1; d < 256; d <<= 1) {
        int tmp = (t >= d) ? sd[t - d] : 0;
        __syncthreads();
        sd[t] += tmp;
        __syncthreads();
    }
    int epre = sd[t] - cnt;         // exclusive prefix within block
    if (t == 255)
        __hip_atomic_store(&chunk_sum[b], sd[255], __ATOMIC_RELEASE, __HIP_MEMORY_SCOPE_AGENT);
    gridbar(bar, 2048);

    // ---- phase C: PARALLEL lookback (masked partial + tree reduce) ----
    int j4 = t * 4;
    int q0 = __hip_atomic_load(&chunk_sum[j4 + 0], __ATOMIC_ACQUIRE, __HIP_MEMORY_SCOPE_AGENT);
    int q1 = __hip_atomic_load(&chunk_sum[j4 + 1], __ATOMIC_ACQUIRE, __HIP_MEMORY_SCOPE_AGENT);
    int q2 = __hip_atomic_load(&chunk_sum[j4 + 2], __ATOMIC_ACQUIRE, __HIP_MEMORY_SCOPE_AGENT);
    int q3 = __hip_atomic_load(&chunk_sum[j4 + 3], __ATOMIC_ACQUIRE, __HIP_MEMORY_SCOPE_AGENT);
    int part = ((j4 + 0) < b ? q0 : 0) + ((j4 + 1) < b ? q1 : 0) +
               ((j4 + 2) < b ? q2 : 0) + ((j4 + 3) < b ? q3 : 0);
    __syncthreads();
    sd[t] = part;
    __syncthreads();
    for (int d = 128; d > 0; d >>= 1) {
        if (t < d) sd[t] += sd[t + d];
        __syncthreads();
    }
    int o = sd[0] + epre;           // global exclusive prefix for cell i
    offs[i] = o;                    // read by build8 (next kernel: boundary-safe)
    __hip_atomic_store(&cursor[i], o, __ATOMIC_RELEASE, __HIP_MEMORY_SCOPE_AGENT);
    if (b == 1023 && t == 255) offs[NN] = K;
    gridbar(bar, 3072);

    // ---- phase D: payload (fused round-2-proven transpose, 2 passes) ----
    sp[t] = atomicAdd(&cursor[cl], 1);   // unique sorted slot for point i
    sw[t] = w;
    __syncthreads();
    int k0 = b * 256;
    int pt = t & 127;
    int ch0 = (t >> 7) * 8;
    int sg = t >> 4, l = t & 15;
    for (int pass = 0; pass < 2; ++pass) {
        int j0 = pass * 128;
#pragma unroll
        for (int cc = 0; cc < 8; ++cc) {
            int c = ch0 + cc;
            tR[pt][c] = xr[(size_t)c * K + k0 + j0 + pt];   // coalesced 512-B reads
            tI[pt][c] = xi[(size_t)c * K + k0 + j0 + pt];
        }
        __syncthreads();
#pragma unroll
        for (int jj = 0; jj < 8; ++jj) {
            int j = sg + jj * 16;
            int pp = sp[j0 + j];
            float ww = sw[j0 + j];
            // 16 lanes write one contiguous 128-B chunk (full HBM granule)
            pay[(size_t)pp * 16 + l] = make_float2(tR[j][l] * ww, tI[j][l] * ww);
        }
        __syncthreads();
    }
}

// ============ fused grid-build + row FFT: atomic-free, barrier-free ============
__global__ __launch_bounds__(256) void build8_kernel(const int* __restrict__ offs,
                                                     const float4* __restrict__ pay4,
                                                     float2* __restrict__ grid) {
    __shared__ float4 lds[4][LROW];   // 34.8 KB
    int bid = blockIdx.x;
    int h = bid & 1;
    int r = bid >> 1;
    int t = threadIdx.x;
    int w = t >> 6;
    int l = t & 63;
    int q = h * 4 + w;                // float4 chunk -> channels 2q, 2q+1
    const int* ro = offs + r * N;

    int sv[8], ev[8];
#pragma unroll
    for (int it = 0; it < 8; ++it) {
        int col = l + (it << 6);
        sv[it] = ro[col];
        ev[it] = ro[col + 1];         // col=511,r=511 reads offs[NN]=K
    }
    float4 vv[8];
#pragma unroll
    for (int it = 0; it < 8; ++it) {  // 8 independent first-point loads in flight
        vv[it] = make_float4(0.f, 0.f, 0.f, 0.f);
        if (sv[it] < ev[it]) vv[it] = pay4[(size_t)sv[it] * 8 + q];
    }
#pragma unroll
    for (int it = 0; it < 8; ++it) {
        float4 acc = vv[it];
        for (int p = sv[it] + 1; p < ev[it]; ++p) {   // rare tail
            float4 v2 = pay4[(size_t)p * 8 + q];
            acc.x += v2.x; acc.y += v2.y; acc.z += v2.z; acc.w += v2.w;
        }
        int col = l + (it << 6);
        int bc = (int)(__brev((unsigned)col) >> (32 - LOG2N));   // bit-reversed col
        lds[w][SK(bc)] = acc;
    }
    asm volatile("s_waitcnt lgkmcnt(0)" ::: "memory");

    // ---- 9 radix-2 DIT stages, +i exponent, wave-local ----
    for (int s = 1; s <= LOG2N; ++s) {
        int half = 1 << (s - 1);
        int m = half << 1;
#pragma unroll
        for (int i = 0; i < 4; ++i) {          // 256 butterflies / 64 lanes
            int b2 = l + (i << 6);
            int j = b2 & (half - 1);
            int grp = b2 >> (s - 1);
            int p1 = grp * m + j;
            int p2 = p1 + half;
            float ang = 6.283185307179586f * (float)j / (float)m;
            float sn, cs;
            __sincosf(ang, &sn, &cs);
            float4 v = lds[w][SK(p2)];
            float4 u = lds[w][SK(p1)];
            float tr0 = cs * v.x - sn * v.y;
            float ti0 = cs * v.y + sn * v.x;
            float tr1 = cs * v.z - sn * v.w;
            float ti1 = cs * v.w + sn * v.z;
            lds[w][SK(p2)] = make_float4(u.x - tr0, u.y - ti0, u.z - tr1, u.w - ti1);
            lds[w][SK(p1)] = make_float4(u.x + tr0, u.y + ti0, u.z + tr1, u.w + ti1);
        }
        asm volatile("s_waitcnt lgkmcnt(0)" ::: "memory");
    }

    // ---- store this wave's 2 channels, coalesced ----
    int c0 = q * 2;
    float2* g0 = grid + (size_t)c0 * NN + (size_t)r * N;
    float2* g1 = grid + (size_t)(c0 + 1) * NN + (size_t)r * N;
    for (int i = l; i < N; i += 64) {
        float4 v = lds[w][SK(i)];
        g0[i] = make_float2(v.x, v.y);
        g1[i] = make_float2(v.z, v.w);
    }
}

// ============ column FFT: NCOL columns per block through LDS (round-2 proven) ============
__global__ __launch_bounds__(256) void colfft_kernel(float2* __restrict__ grid) {
    __shared__ float sr[N * NCOL];
    __shared__ float si[N * NCOL];
    int blk = blockIdx.x;                        // c * (N/NCOL) + cg
    int c = blk >> 6;
    int cg = blk & 63;
    float2* base = grid + (size_t)c * NN + cg * NCOL;
    int t = threadIdx.x;

    for (int e = t; e < N * NCOL; e += 256) {
        int row = e >> 3, col = e & 7;
        float2 v = base[(size_t)row * N + col];
        sr[e] = v.x; si[e] = v.y;
    }
    __syncthreads();

    int col = t & 7;
    int tg = t >> 3;
    for (int i = tg; i < N; i += 32) {
        int j = __brev((unsigned)i) >> (32 - LOG2N);
        if (j > i) {
            int a1 = i * NCOL + col, a2 = j * NCOL + col;
            float a = sr[a1]; sr[a1] = sr[a2]; sr[a2] = a;
            float b = si[a1]; si[a1] = si[a2]; si[a2] = b;
        }
    }
    __syncthreads();

    for (int s = 1; s <= LOG2N; ++s) {
        int half = 1 << (s - 1);
        int m = half << 1;
        for (int b = tg; b < 256; b += 32) {
            int j = b & (half - 1);
            int grp = b >> (s - 1);
            int p1 = grp * m + j;
            int p2 = p1 + half;
            float ang = 6.283185307179586f * (float)j / (float)m;
            float sn, cs;
            __sincosf(ang, &sn, &cs);
            int a1 = p1 * NCOL + col, a2 = p2 * NCOL + col;
            float xr2 = sr[a2], xi2 = si[a2];
            float tr = cs * xr2 - sn * xi2;
            float ti = cs * xi2 + sn * xr2;
            float ur = sr[a1], ui = si[a1];
            sr[a2] = ur - tr; si[a2] = ui - ti;
            sr[a1] = ur + tr; si[a1] = ui + ti;
        }
        __syncthreads();
    }

    for (int e = t; e < N * NCOL; e += 256) {
        int row = e >> 3, col2 = e & 7;
        base[(size_t)row * N + col2] = make_float2(sr[e], si[e]);
    }
}

// ============ combine: out = (-1)^(ny+nx) * sum_c conj(csm)*img (round-2 proven) ============
__global__ __launch_bounds__(256) void combine_kernel(const float* __restrict__ csr,
                                                      const float* __restrict__ csi,
                                                      const float2* __restrict__ grid,
                                                      float* __restrict__ out) {
    int pix = blockIdx.x * 256 + threadIdx.x;
    int ny = pix >> LOG2N, nx = pix & (N - 1);
    float ar = 0.f, ai = 0.f;
#pragma unroll
    for (int c = 0; c < C; ++c) {
        float2 uv = grid[(size_t)c * NN + pix];
        float a = csr[c * NN + pix];
        float b = csi[c * NN + pix];
        ar += a * uv.x + b * uv.y;
        ai += a * uv.y - b * uv.x;
    }
    float s = ((ny + nx) & 1) ? -1.f : 1.f;      // fftshift folded into output sign
    out[pix] = s * ar;
    out[NN + pix] = s * ai;
}

extern "C" void kernel_launch(void* const* d_in, const int* in_sizes, int n_in,
                              void* d_out, int out_size, void* d_ws, size_t ws_size,
                              hipStream_t stream) {
    const float* x_real   = (const float*)d_in[0];
    const float* x_imag   = (const float*)d_in[1];
    const float* csm_real = (const float*)d_in[2];
    const float* csm_imag = (const float*)d_in[3];
    const float2* traj    = (const float2*)d_in[4];
    const float* dcf      = (const float*)d_in[5];
    float* out = (float*)d_out;

    char* ws = (char*)d_ws;
    size_t o = 0;
    float* grid  = (float*)(ws + o); o += (size_t)C * NN * 2 * sizeof(float);  // 32 MB
    int*   count = (int*)(ws + o);   o += (size_t)NN * sizeof(int);            // 1 MB
    int*   bar   = (int*)(ws + o);   o += 64;                                  // zeroed with count
    int*   offs  = (int*)(ws + o);   o += ((size_t)NN + 4) * sizeof(int);      // 1 MB (+pad)
    int*   cursor= (int*)(ws + o);   o += (size_t)NN * sizeof(int);            // 1 MB
    float2* pay  = (float2*)(ws + o); o += (size_t)K * 16 * sizeof(float2);    // 32 MB
    int*   chunk_sum = (int*)(ws + o); o += 1024 * sizeof(int);

    // one memset zeroes count AND the grid-barrier counter
    (void)hipMemsetAsync(count, 0, (size_t)NN * sizeof(int) + 64, stream);

    scan_pay_kernel<<<1024, 256, 0, stream>>>(traj, dcf, x_real, x_imag,
                                              count, offs, cursor, chunk_sum, bar, pay);
    build8_kernel<<<N * 2, 256, 0, stream>>>(offs, (const float4*)pay, (float2*)grid);
    colfft_kernel<<<C * (N / NCOL), 256, 0, stream>>>((float2*)grid);
    combine_kernel<<<NN / 256, 256, 0, stream>>>(csm_real, csm_imag, (float2*)grid, out);
}

// Round 6
// 211.384 us; speedup vs baseline: 2.6475x; 2.6475x over previous
//
#include <hip/hip_runtime.h>
#include <math.h>

#define N 512
#define NN (N * N)
#define C 16
#define K 262144
#define LOG2N 9

// skewed LDS addressing (float4-element units): +1 every 16 elements.
// Makes bit-reversed scatter writes and stride-2^s butterfly b128 accesses
// hit the LDS bank floor instead of 8-16-way conflicts.
#define SK(e) ((e) + ((e) >> 4))
#define LROW 544   // 512 + 32 skew slack

// ============ phase 1: bin points by cell (counting sort, round-2 proven) ============

__global__ __launch_bounds__(256) void prep_hist_kernel(const float2* __restrict__ traj,
                                                        const float* __restrict__ dcf,
                                                        int* __restrict__ cell,
                                                        float* __restrict__ sdcf,
                                                        int* __restrict__ count) {
    int k = blockIdx.x * 256 + threadIdx.x;
    float2 t = traj[k];
    int iy = __float2int_rn((t.x + 0.5f) * (float)N) & (N - 1);
    int ix = __float2int_rn((t.y + 0.5f) * (float)N) & (N - 1);
    int cl = iy * N + ix;
    cell[k] = cl;
    float s = ((iy + ix) & 1) ? -1.0f : 1.0f;   // ifftshift folded into input sign
    sdcf[k] = dcf[k] * s;
    atomicAdd(&count[cl], 1);
}

__global__ __launch_bounds__(256) void scan_reduce_kernel(const int* __restrict__ count,
                                                          int* __restrict__ bsum) {
    __shared__ int sd[256];
    int t = threadIdx.x;
    const int4* c4 = (const int4*)count;
    int4 v = c4[blockIdx.x * 256 + t];
    sd[t] = v.x + v.y + v.z + v.w;
    __syncthreads();
    for (int d = 128; d > 0; d >>= 1) {
        if (t < d) sd[t] += sd[t + d];
        __syncthreads();
    }
    if (t == 0) bsum[blockIdx.x] = sd[0];
}

__global__ __launch_bounds__(256) void scan_top_kernel(const int* __restrict__ bsum,
                                                       int* __restrict__ boffs,
                                                       int* __restrict__ offs) {
    __shared__ int sd[256];
    int t = threadIdx.x;
    int v = bsum[t];
    sd[t] = v;
    __syncthreads();
    for (int d = 1; d < 256; d <<= 1) {
        int tmp = (t >= d) ? sd[t - d] : 0;
        __syncthreads();
        sd[t] += tmp;
        __syncthreads();
    }
    boffs[t] = sd[t] - v;
    if (t == 0) offs[NN] = K;
}

__global__ __launch_bounds__(256) void scan_final_kernel(const int* __restrict__ count,
                                                         const int* __restrict__ boffs,
                                                         int* __restrict__ offs,
                                                         int* __restrict__ cursor) {
    __shared__ int sd[256];
    int t = threadIdx.x;
    int base_idx = blockIdx.x * 256 + t;
    const int4* c4 = (const int4*)count;
    int4 v = c4[base_idx];
    int s = v.x + v.y + v.z + v.w;
    sd[t] = s;
    __syncthreads();
    for (int d = 1; d < 256; d <<= 1) {
        int tmp = (t >= d) ? sd[t - d] : 0;
        __syncthreads();
        sd[t] += tmp;
        __syncthreads();
    }
    int base = boffs[blockIdx.x] + sd[t] - s;
    int4 o;
    o.x = base;
    o.y = base + v.x;
    o.z = base + v.x + v.y;
    o.w = base + v.x + v.y + v.z;
    ((int4*)offs)[base_idx] = o;
    ((int4*)cursor)[base_idx] = o;
}

// ============ payload build: transpose x to sorted point order (rounds 3-4 proven) ============
__global__ __launch_bounds__(256) void payload_kernel(const float* __restrict__ xr,
                                                      const float* __restrict__ xi,
                                                      const int* __restrict__ cell,
                                                      const float* __restrict__ sdcf,
                                                      int* __restrict__ cursor,
                                                      float2* __restrict__ pay) {
    __shared__ float tR[256][17];   // [point][channel], +1 pad -> conflict-free
    __shared__ float tI[256][17];
    __shared__ int   sp[256];
    __shared__ float sw[256];
    int t = threadIdx.x;
    int k0 = blockIdx.x * 256;
#pragma unroll
    for (int c = 0; c < C; ++c) {
        tR[t][c] = xr[(size_t)c * K + k0 + t];   // coalesced 1-KB reads
        tI[t][c] = xi[(size_t)c * K + k0 + t];
    }
    int cl = cell[k0 + t];
    float w = sdcf[k0 + t];
    sp[t] = atomicAdd(&cursor[cl], 1);           // unique sorted slot
    sw[t] = w;
    __syncthreads();
    int sg = t >> 4, l = t & 15;                 // 16 subgroups of 16 lanes
    for (int j = sg; j < 256; j += 16) {
        int pp = sp[j];
        float ww = sw[j];
        // 16 lanes write one contiguous 128-B chunk (full HBM granule)
        pay[(size_t)pp * 16 + l] = make_float2(tR[j][l] * ww, tI[j][l] * ww);
    }
}

// ============ fused grid-build + row FFT: atomic-free, barrier-free (round-4 proven) ============
__global__ __launch_bounds__(256) void build8_kernel(const int* __restrict__ offs,
                                                     const float4* __restrict__ pay4,
                                                     float2* __restrict__ grid) {
    __shared__ float4 lds[4][LROW];   // 34.8 KB
    int bid = blockIdx.x;
    int h = bid & 1;
    int r = bid >> 1;
    int t = threadIdx.x;
    int w = t >> 6;
    int l = t & 63;
    int q = h * 4 + w;                // float4 chunk -> channels 2q, 2q+1
    const int* ro = offs + r * N;

    int sv[8], ev[8];
#pragma unroll
    for (int it = 0; it < 8; ++it) {
        int col = l + (it << 6);
        sv[it] = ro[col];
        ev[it] = ro[col + 1];         // col=511,r=511 reads offs[NN]=K
    }
    float4 vv[8];
#pragma unroll
    for (int it = 0; it < 8; ++it) {  // 8 independent first-point loads in flight
        vv[it] = make_float4(0.f, 0.f, 0.f, 0.f);
        if (sv[it] < ev[it]) vv[it] = pay4[(size_t)sv[it] * 8 + q];
    }
#pragma unroll
    for (int it = 0; it < 8; ++it) {
        float4 acc = vv[it];
        for (int p = sv[it] + 1; p < ev[it]; ++p) {   // rare tail
            float4 v2 = pay4[(size_t)p * 8 + q];
            acc.x += v2.x; acc.y += v2.y; acc.z += v2.z; acc.w += v2.w;
        }
        int col = l + (it << 6);
        int bc = (int)(__brev((unsigned)col) >> (32 - LOG2N));   // bit-reversed col
        lds[w][SK(bc)] = acc;
    }
    asm volatile("s_waitcnt lgkmcnt(0)" ::: "memory");

    // ---- 9 radix-2 DIT stages, +i exponent, wave-local ----
    for (int s = 1; s <= LOG2N; ++s) {
        int half = 1 << (s - 1);
        int m = half << 1;
#pragma unroll
        for (int i = 0; i < 4; ++i) {          // 256 butterflies / 64 lanes
            int b2 = l + (i << 6);
            int j = b2 & (half - 1);
            int grp = b2 >> (s - 1);
            int p1 = grp * m + j;
            int p2 = p1 + half;
            float ang = 6.283185307179586f * (float)j / (float)m;
            float sn, cs;
            __sincosf(ang, &sn, &cs);
            float4 v = lds[w][SK(p2)];
            float4 u = lds[w][SK(p1)];
            float tr0 = cs * v.x - sn * v.y;
            float ti0 = cs * v.y + sn * v.x;
            float tr1 = cs * v.z - sn * v.w;
            float ti1 = cs * v.w + sn * v.z;
            lds[w][SK(p2)] = make_float4(u.x - tr0, u.y - ti0, u.z - tr1, u.w - ti1);
            lds[w][SK(p1)] = make_float4(u.x + tr0, u.y + ti0, u.z + tr1, u.w + ti1);
        }
        asm volatile("s_waitcnt lgkmcnt(0)" ::: "memory");
    }

    // ---- store this wave's 2 channels, coalesced ----
    int c0 = q * 2;
    float2* g0 = grid + (size_t)c0 * NN + (size_t)r * N;
    float2* g1 = grid + (size_t)(c0 + 1) * NN + (size_t)r * N;
    for (int i = l; i < N; i += 64) {
        float4 v = lds[w][SK(i)];
        g0[i] = make_float2(v.x, v.y);
        g1[i] = make_float2(v.z, v.w);
    }
}

// ============ column FFT: wave-local, barrier-free (build8 structure ported) ============
// block = (channel c, 8-column group cg); wave w owns 2 adjacent columns in a
// private skewed float4 stripe. Per row the block touches a full 64-B line
// (8 cols x 8 B). Bit-reversal folded into the load scatter. No __syncthreads;
// stage ordering via s_waitcnt lgkmcnt(0). Twiddles shared across 2 columns.
__global__ __launch_bounds__(256) void colfft_kernel(float2* __restrict__ grid) {
    __shared__ float4 lds[4][LROW];   // 34.8 KB
    int blk = blockIdx.x;             // c * 64 + cg
    int c = blk >> 6;
    int cg = blk & 63;
    int t = threadIdx.x;
    int w = t >> 6;
    int l = t & 63;
    int colb = cg * 8 + w * 2;        // this wave's 2 columns
    float2* gp = grid + (size_t)c * NN + colb;

    // ---- load 8 rows/lane as float4 (2 cols), scatter bit-reversed ----
#pragma unroll
    for (int j = 0; j < 8; ++j) {
        int row = l + (j << 6);
        float4 v = *(const float4*)(gp + (size_t)row * N);
        int br = (int)(__brev((unsigned)row) >> (32 - LOG2N));
        lds[w][SK(br)] = v;
    }
    asm volatile("s_waitcnt lgkmcnt(0)" ::: "memory");

    // ---- 9 radix-2 DIT stages, +i exponent, wave-local ----
    for (int s = 1; s <= LOG2N; ++s) {
        int half = 1 << (s - 1);
        int m = half << 1;
#pragma unroll
        for (int i = 0; i < 4; ++i) {
            int b2 = l + (i << 6);
            int j = b2 & (half - 1);
            int grp = b2 >> (s - 1);
            int p1 = grp * m + j;
            int p2 = p1 + half;
            float ang = 6.283185307179586f * (float)j / (float)m;
            float sn, cs;
            __sincosf(ang, &sn, &cs);
            float4 v = lds[w][SK(p2)];
            float4 u = lds[w][SK(p1)];
            float tr0 = cs * v.x - sn * v.y;
            float ti0 = cs * v.y + sn * v.x;
            float tr1 = cs * v.z - sn * v.w;
            float ti1 = cs * v.w + sn * v.z;
            lds[w][SK(p2)] = make_float4(u.x - tr0, u.y - ti0, u.z - tr1, u.w - ti1);
            lds[w][SK(p1)] = make_float4(u.x + tr0, u.y + ti0, u.z + tr1, u.w + ti1);
        }
        asm volatile("s_waitcnt lgkmcnt(0)" ::: "memory");
    }

    // ---- store natural order, float4 (2 cols per lane-row) ----
#pragma unroll
    for (int j = 0; j < 8; ++j) {
        int i = l + (j << 6);
        *(float4*)(gp + (size_t)i * N) = lds[w][SK(i)];
    }
}

// ============ combine: out = (-1)^(ny+nx) * sum_c conj(csm)*img (round-2 proven) ============
__global__ __launch_bounds__(256) void combine_kernel(const float* __restrict__ csr,
                                                      const float* __restrict__ csi,
                                                      const float2* __restrict__ grid,
                                                      float* __restrict__ out) {
    int pix = blockIdx.x * 256 + threadIdx.x;
    int ny = pix >> LOG2N, nx = pix & (N - 1);
    float ar = 0.f, ai = 0.f;
#pragma unroll
    for (int c = 0; c < C; ++c) {
        float2 uv = grid[(size_t)c * NN + pix];
        float a = csr[c * NN + pix];
        float b = csi[c * NN + pix];
        ar += a * uv.x + b * uv.y;
        ai += a * uv.y - b * uv.x;
    }
    float s = ((ny + nx) & 1) ? -1.f : 1.f;      // fftshift folded into output sign
    out[pix] = s * ar;
    out[NN + pix] = s * ai;
}

extern "C" void kernel_launch(void* const* d_in, const int* in_sizes, int n_in,
                              void* d_out, int out_size, void* d_ws, size_t ws_size,
                              hipStream_t stream) {
    const float* x_real   = (const float*)d_in[0];
    const float* x_imag   = (const float*)d_in[1];
    const float* csm_real = (const float*)d_in[2];
    const float* csm_imag = (const float*)d_in[3];
    const float2* traj    = (const float2*)d_in[4];
    const float* dcf      = (const float*)d_in[5];
    float* out = (float*)d_out;

    char* ws = (char*)d_ws;
    size_t o = 0;
    float* grid  = (float*)(ws + o); o += (size_t)C * NN * 2 * sizeof(float);  // 32 MB
    int*   cell  = (int*)(ws + o);   o += (size_t)K * sizeof(int);             // 1 MB
    float* sdcf  = (float*)(ws + o); o += (size_t)K * sizeof(float);           // 1 MB
    int*   count = (int*)(ws + o);   o += (size_t)NN * sizeof(int);            // 1 MB
    int*   offs  = (int*)(ws + o);   o += ((size_t)NN + 4) * sizeof(int);      // 1 MB (+pad)
    int*   cursor= (int*)(ws + o);   o += (size_t)NN * sizeof(int);            // 1 MB
    float2* pay  = (float2*)(ws + o); o += (size_t)K * 16 * sizeof(float2);    // 32 MB
    int*   bsum  = (int*)(ws + o);   o += 256 * sizeof(int);
    int*   boffs = (int*)(ws + o);   o += 256 * sizeof(int);

    (void)hipMemsetAsync(count, 0, (size_t)NN * sizeof(int), stream);

    prep_hist_kernel<<<K / 256, 256, 0, stream>>>(traj, dcf, cell, sdcf, count);
    scan_reduce_kernel<<<256, 256, 0, stream>>>(count, bsum);
    scan_top_kernel<<<1, 256, 0, stream>>>(bsum, boffs, offs);
    scan_final_kernel<<<256, 256, 0, stream>>>(count, boffs, offs, cursor);
    payload_kernel<<<K / 256, 256, 0, stream>>>(x_real, x_imag, cell, sdcf, cursor, pay);
    build8_kernel<<<N * 2, 256, 0, stream>>>(offs, (const float4*)pay, (float2*)grid);
    colfft_kernel<<<C * 64, 256, 0, stream>>>((float2*)grid);
    combine_kernel<<<NN / 256, 256, 0, stream>>>(csm_real, csm_imag, (float2*)grid, out);
}

// Round 7
// 200.002 us; speedup vs baseline: 2.7982x; 1.0569x over previous
//
#include <hip/hip_runtime.h>
#include <math.h>

#define N 512
#define NN (N * N)
#define C 16
#define K 262144
#define LOG2N 9

// skewed LDS addressing (float4-element units): +1 every 16 elements.
#define SK(e) ((e) + ((e) >> 4))
#define LROW 544   // 512 + 32 skew slack

// ============ radix-4 butterfly on a wave-private float4 stripe ============
// Exact fusion of radix-2 DIT stages (s, s+1), h = 2^(s-1):
//   group (p0, p0+h, p0+2h, p0+3h), j = p0 mod h
//   stage s:   t=W_{2h}^j x1; e0=x0+t, e1=x0-t;  t2=W_{2h}^j x3; e2=x2+t2, e3=x2-t2
//   stage s+1: u=W_{4h}^j e2; y0=e0+u, y2=e0-u;  v=i W_{4h}^j e3; y1=e1+v, y3=e1-v
// (+i exponent convention = ifft). float4 = 2 independent complex values.
__device__ __forceinline__ void rad4(float4* stripe, int p0, int h,
                                     float c1, float s1, float c2, float s2) {
    float4 x0 = stripe[SK(p0)];
    float4 x1 = stripe[SK(p0 + h)];
    float4 x2 = stripe[SK(p0 + 2 * h)];
    float4 x3 = stripe[SK(p0 + 3 * h)];
    float4 t, e0, e1, e2, e3, u, v;
    t.x = c1 * x1.x - s1 * x1.y;  t.y = c1 * x1.y + s1 * x1.x;
    t.z = c1 * x1.z - s1 * x1.w;  t.w = c1 * x1.w + s1 * x1.z;
    e0 = make_float4(x0.x + t.x, x0.y + t.y, x0.z + t.z, x0.w + t.w);
    e1 = make_float4(x0.x - t.x, x0.y - t.y, x0.z - t.z, x0.w - t.w);
    t.x = c1 * x3.x - s1 * x3.y;  t.y = c1 * x3.y + s1 * x3.x;
    t.z = c1 * x3.z - s1 * x3.w;  t.w = c1 * x3.w + s1 * x3.z;
    e2 = make_float4(x2.x + t.x, x2.y + t.y, x2.z + t.z, x2.w + t.w);
    e3 = make_float4(x2.x - t.x, x2.y - t.y, x2.z - t.z, x2.w - t.w);
    u.x = c2 * e2.x - s2 * e2.y;  u.y = c2 * e2.y + s2 * e2.x;
    u.z = c2 * e2.z - s2 * e2.w;  u.w = c2 * e2.w + s2 * e2.z;
    stripe[SK(p0)]         = make_float4(e0.x + u.x, e0.y + u.y, e0.z + u.z, e0.w + u.w);
    stripe[SK(p0 + 2 * h)] = make_float4(e0.x - u.x, e0.y - u.y, e0.z - u.z, e0.w - u.w);
    v.x = -s2 * e3.x - c2 * e3.y;  v.y = c2 * e3.x - s2 * e3.y;   // i*W2 = -s2 + i c2
    v.z = -s2 * e3.z - c2 * e3.w;  v.w = c2 * e3.z - s2 * e3.w;
    stripe[SK(p0 + h)]     = make_float4(e1.x + v.x, e1.y + v.y, e1.z + v.z, e1.w + v.w);
    stripe[SK(p0 + 3 * h)] = make_float4(e1.x - v.x, e1.y - v.y, e1.z - v.z, e1.w - v.w);
}

// 512-pt FFT, input bit-reversed, output natural; 4 fused radix-4 stages
// (radix-2 pairs 1&2, 3&4, 5&6, 7&8) + final radix-2 stage 9. Wave-local:
// stage ordering via s_waitcnt lgkmcnt(0); zero __syncthreads.
__device__ __forceinline__ void fft512_wave(float4* stripe, int l) {
    // fs=0 (h=1): all twiddles trivial (W=1, iW=i) -> constant-folded
#pragma unroll
    for (int i = 0; i < 2; ++i) {
        int g = l + (i << 6);
        rad4(stripe, g * 4, 1, 1.f, 0.f, 1.f, 0.f);
    }
    asm volatile("s_waitcnt lgkmcnt(0)" ::: "memory");
#pragma unroll
    for (int fs = 1; fs < 4; ++fs) {
        int h = 1 << (2 * fs);
#pragma unroll
        for (int i = 0; i < 2; ++i) {
            int g = l + (i << 6);
            int j = g & (h - 1);
            int grp = g >> (2 * fs);
            int p0 = (grp << (2 * fs + 2)) + j;
            float a1 = 6.283185307179586f * (float)j / (float)(2 * h);
            float a2 = 0.5f * a1;                    // 2*pi*j/(4h)
            float s1, c1, s2, c2;
            __sincosf(a1, &s1, &c1);
            __sincosf(a2, &s2, &c2);
            rad4(stripe, p0, h, c1, s1, c2, s2);
        }
        asm volatile("s_waitcnt lgkmcnt(0)" ::: "memory");
    }
    // final radix-2 stage: half = 256
#pragma unroll
    for (int i = 0; i < 4; ++i) {
        int b2 = l + (i << 6);
        float ang = 6.283185307179586f * (float)b2 * (1.0f / 512.0f);
        float sn, cs;
        __sincosf(ang, &sn, &cs);
        float4 v = stripe[SK(b2 + 256)];
        float4 u = stripe[SK(b2)];
        float tr0 = cs * v.x - sn * v.y;
        float ti0 = cs * v.y + sn * v.x;
        float tr1 = cs * v.z - sn * v.w;
        float ti1 = cs * v.w + sn * v.z;
        stripe[SK(b2 + 256)] = make_float4(u.x - tr0, u.y - ti0, u.z - tr1, u.w - ti1);
        stripe[SK(b2)]       = make_float4(u.x + tr0, u.y + ti0, u.z + tr1, u.w + ti1);
    }
    asm volatile("s_waitcnt lgkmcnt(0)" ::: "memory");
}

// ============ phase 1: bin points by cell (counting sort) ============

__global__ __launch_bounds__(256) void prep_hist_kernel(const float2* __restrict__ traj,
                                                        const float* __restrict__ dcf,
                                                        float2* __restrict__ cw,
                                                        int* __restrict__ count) {
    int k = blockIdx.x * 256 + threadIdx.x;
    float2 t = traj[k];
    int iy = __float2int_rn((t.x + 0.5f) * (float)N) & (N - 1);
    int ix = __float2int_rn((t.y + 0.5f) * (float)N) & (N - 1);
    int cl = iy * N + ix;
    float s = ((iy + ix) & 1) ? -1.0f : 1.0f;   // ifftshift folded into input sign
    cw[k] = make_float2(__int_as_float(cl), dcf[k] * s);   // packed {cell, signed dcf}
    atomicAdd(&count[cl], 1);
}

__global__ __launch_bounds__(256) void scan_reduce_kernel(const int* __restrict__ count,
                                                          int* __restrict__ bsum) {
    __shared__ int sd[256];
    int t = threadIdx.x;
    const int4* c4 = (const int4*)count;
    int4 v = c4[blockIdx.x * 256 + t];
    sd[t] = v.x + v.y + v.z + v.w;
    __syncthreads();
    for (int d = 128; d > 0; d >>= 1) {
        if (t < d) sd[t] += sd[t + d];
        __syncthreads();
    }
    if (t == 0) bsum[blockIdx.x] = sd[0];
}

// merged scan_top + scan_final: every block redundantly scans bsum[256] (1 KB)
__global__ __launch_bounds__(256) void scan_final2_kernel(const int* __restrict__ count,
                                                          const int* __restrict__ bsum,
                                                          int* __restrict__ offs,
                                                          int* __restrict__ cursor) {
    __shared__ int sb[256];
    __shared__ int sd[256];
    int t = threadIdx.x;
    int b = blockIdx.x;
    int vb = bsum[t];
    sb[t] = vb;
    __syncthreads();
    for (int d = 1; d < 256; d <<= 1) {
        int tmp = (t >= d) ? sb[t - d] : 0;
        __syncthreads();
        sb[t] += tmp;
        __syncthreads();
    }
    int4 c4 = ((const int4*)count)[b * 256 + t];
    int s = c4.x + c4.y + c4.z + c4.w;
    sd[t] = s;
    __syncthreads();
    for (int d = 1; d < 256; d <<= 1) {
        int tmp = (t >= d) ? sd[t - d] : 0;
        __syncthreads();
        sd[t] += tmp;
        __syncthreads();
    }
    int bexc = sb[b] - bsum[b];          // exclusive prefix of this block's chunk
    int base = bexc + sd[t] - s;
    int4 o;
    o.x = base;
    o.y = base + c4.x;
    o.z = base + c4.x + c4.y;
    o.w = base + c4.x + c4.y + c4.z;
    ((int4*)offs)[b * 256 + t] = o;
    ((int4*)cursor)[b * 256 + t] = o;
    if (b == 0 && t == 0) offs[NN] = K;
}

// ============ payload build: transpose x to sorted point order ============
__global__ __launch_bounds__(256) void payload_kernel(const float* __restrict__ xr,
                                                      const float* __restrict__ xi,
                                                      const float2* __restrict__ cw,
                                                      int* __restrict__ cursor,
                                                      float2* __restrict__ pay) {
    __shared__ float tR[256][17];   // [point][channel], +1 pad -> conflict-free
    __shared__ float tI[256][17];
    __shared__ int   sp[256];
    __shared__ float sw[256];
    int t = threadIdx.x;
    int k0 = blockIdx.x * 256;
#pragma unroll
    for (int c = 0; c < C; ++c) {
        tR[t][c] = xr[(size_t)c * K + k0 + t];   // coalesced 1-KB reads
        tI[t][c] = xi[(size_t)c * K + k0 + t];
    }
    float2 cwv = cw[k0 + t];
    int cl = __float_as_int(cwv.x);
    sp[t] = atomicAdd(&cursor[cl], 1);           // unique sorted slot
    sw[t] = cwv.y;
    __syncthreads();
    int sg = t >> 4, l = t & 15;                 // 16 subgroups of 16 lanes
    for (int j = sg; j < 256; j += 16) {
        int pp = sp[j];
        float ww = sw[j];
        // 16 lanes write one contiguous 128-B chunk (full HBM granule)
        pay[(size_t)pp * 16 + l] = make_float2(tR[j][l] * ww, tI[j][l] * ww);
    }
}

// ============ fused grid-build + row FFT: atomic-free, barrier-free ============
__global__ __launch_bounds__(256) void build8_kernel(const int* __restrict__ offs,
                                                     const float4* __restrict__ pay4,
                                                     float2* __restrict__ grid) {
    __shared__ float4 lds[4][LROW];   // 34.8 KB
    int bid = blockIdx.x;
    int h = bid & 1;
    int r = bid >> 1;
    int t = threadIdx.x;
    int w = t >> 6;
    int l = t & 63;
    int q = h * 4 + w;                // float4 chunk -> channels 2q, 2q+1
    const int* ro = offs + r * N;

    int sv[8], ev[8];
#pragma unroll
    for (int it = 0; it < 8; ++it) {
        int col = l + (it << 6);
        sv[it] = ro[col];
        ev[it] = ro[col + 1];         // col=511,r=511 reads offs[NN]=K
    }
    // prefetch first TWO points per cell (covers 92% of cells), all in flight
    float4 vv[8], vv2[8];
#pragma unroll
    for (int it = 0; it < 8; ++it) {
        vv[it] = make_float4(0.f, 0.f, 0.f, 0.f);
        if (sv[it] < ev[it]) vv[it] = pay4[(size_t)sv[it] * 8 + q];
    }
#pragma unroll
    for (int it = 0; it < 8; ++it) {
        vv2[it] = make_float4(0.f, 0.f, 0.f, 0.f);
        if (sv[it] + 1 < ev[it]) vv2[it] = pay4[(size_t)(sv[it] + 1) * 8 + q];
    }
#pragma unroll
    for (int it = 0; it < 8; ++it) {
        float4 acc = make_float4(vv[it].x + vv2[it].x, vv[it].y + vv2[it].y,
                                 vv[it].z + vv2[it].z, vv[it].w + vv2[it].w);
        for (int p = sv[it] + 2; p < ev[it]; ++p) {   // rare tail (8% of cells)
            float4 v2 = pay4[(size_t)p * 8 + q];
            acc.x += v2.x; acc.y += v2.y; acc.z += v2.z; acc.w += v2.w;
        }
        int col = l + (it << 6);
        int bc = (int)(__brev((unsigned)col) >> (32 - LOG2N));   // bit-reversed col
        lds[w][SK(bc)] = acc;
    }
    asm volatile("s_waitcnt lgkmcnt(0)" ::: "memory");

    fft512_wave(&lds[w][0], l);

    // ---- store this wave's 2 channels, coalesced ----
    int c0 = q * 2;
    float2* g0 = grid + (size_t)c0 * NN + (size_t)r * N;
    float2* g1 = grid + (size_t)(c0 + 1) * NN + (size_t)r * N;
    for (int i = l; i < N; i += 64) {
        float4 v = lds[w][SK(i)];
        g0[i] = make_float2(v.x, v.y);
        g1[i] = make_float2(v.z, v.w);
    }
}

// ============ column FFT: wave-local, barrier-free ============
__global__ __launch_bounds__(256) void colfft_kernel(float2* __restrict__ grid) {
    __shared__ float4 lds[4][LROW];   // 34.8 KB
    int blk = blockIdx.x;             // c * 64 + cg
    int c = blk >> 6;
    int cg = blk & 63;
    int t = threadIdx.x;
    int w = t >> 6;
    int l = t & 63;
    int colb = cg * 8 + w * 2;        // this wave's 2 columns
    float2* gp = grid + (size_t)c * NN + colb;

    // ---- load 8 rows/lane as float4 (2 cols), scatter bit-reversed ----
#pragma unroll
    for (int j = 0; j < 8; ++j) {
        int row = l + (j << 6);
        float4 v = *(const float4*)(gp + (size_t)row * N);
        int br = (int)(__brev((unsigned)row) >> (32 - LOG2N));
        lds[w][SK(br)] = v;
    }
    asm volatile("s_waitcnt lgkmcnt(0)" ::: "memory");

    fft512_wave(&lds[w][0], l);

    // ---- store natural order, float4 (2 cols per lane-row) ----
#pragma unroll
    for (int j = 0; j < 8; ++j) {
        int i = l + (j << 6);
        *(float4*)(gp + (size_t)i * N) = lds[w][SK(i)];
    }
}

// ============ combine: out = (-1)^(ny+nx) * sum_c conj(csm)*img ============
__global__ __launch_bounds__(256) void combine_kernel(const float* __restrict__ csr,
                                                      const float* __restrict__ csi,
                                                      const float2* __restrict__ grid,
                                                      float* __restrict__ out) {
    int pix = blockIdx.x * 256 + threadIdx.x;
    int ny = pix >> LOG2N, nx = pix & (N - 1);
    float ar = 0.f, ai = 0.f;
#pragma unroll
    for (int c = 0; c < C; ++c) {
        float2 uv = grid[(size_t)c * NN + pix];
        float a = csr[c * NN + pix];
        float b = csi[c * NN + pix];
        ar += a * uv.x + b * uv.y;
        ai += a * uv.y - b * uv.x;
    }
    float s = ((ny + nx) & 1) ? -1.f : 1.f;      // fftshift folded into output sign
    out[pix] = s * ar;
    out[NN + pix] = s * ai;
}

extern "C" void kernel_launch(void* const* d_in, const int* in_sizes, int n_in,
                              void* d_out, int out_size, void* d_ws, size_t ws_size,
                              hipStream_t stream) {
    const float* x_real   = (const float*)d_in[0];
    const float* x_imag   = (const float*)d_in[1];
    const float* csm_real = (const float*)d_in[2];
    const float* csm_imag = (const float*)d_in[3];
    const float2* traj    = (const float2*)d_in[4];
    const float* dcf      = (const float*)d_in[5];
    float* out = (float*)d_out;

    char* ws = (char*)d_ws;
    size_t o = 0;
    float* grid  = (float*)(ws + o); o += (size_t)C * NN * 2 * sizeof(float);  // 32 MB
    float2* cw   = (float2*)(ws + o); o += (size_t)K * sizeof(float2);         // 2 MB
    int*   count = (int*)(ws + o);   o += (size_t)NN * sizeof(int);            // 1 MB
    int*   offs  = (int*)(ws + o);   o += ((size_t)NN + 4) * sizeof(int);      // 1 MB (+pad)
    int*   cursor= (int*)(ws + o);   o += (size_t)NN * sizeof(int);            // 1 MB
    float2* pay  = (float2*)(ws + o); o += (size_t)K * 16 * sizeof(float2);    // 32 MB
    int*   bsum  = (int*)(ws + o);   o += 256 * sizeof(int);

    (void)hipMemsetAsync(count, 0, (size_t)NN * sizeof(int), stream);

    prep_hist_kernel<<<K / 256, 256, 0, stream>>>(traj, dcf, cw, count);
    scan_reduce_kernel<<<256, 256, 0, stream>>>(count, bsum);
    scan_final2_kernel<<<256, 256, 0, stream>>>(count, bsum, offs, cursor);
    payload_kernel<<<K / 256, 256, 0, stream>>>(x_real, x_imag, cw, cursor, pay);
    build8_kernel<<<N * 2, 256, 0, stream>>>(offs, (const float4*)pay, (float2*)grid);
    colfft_kernel<<<C * 64, 256, 0, stream>>>((float2*)grid);
    combine_kernel<<<NN / 256, 256, 0, stream>>>(csm_real, csm_imag, (float2*)grid, out);
}